// Round 11
// baseline (1142.066 us; speedup 1.0000x reference)
//
#include <hip/hip_runtime.h>
#include <hip/hip_bf16.h>

#define NSLOT 30
#define BB    16
#define TT    8
#define SS    400
#define HH    400
#define KP    416           // K padded to 13*32 for MFMA
#define NKK   13            // KP/32
#define VV    20000
#define GG    3
#define BSR   480           // NSLOT*BB fused decode rows
#define NBN   157           // ceil(VV/128) col-blocks
#define NCT   1256          // NBN*8 col tiles in emb frag buffer (zero-padded)
#define NG2   1200          // gemm2 output cols (3*HH)
#define NCT2  75            // NG2/16 col tiles for W frags
#define NRT   30            // BSR/16 row tiles (rg-layout)
#define NST   25            // s-tiles for encA frags (400/16)
#define FRAG_STRIDE 512     // shorts per (tile,kk): 64 lanes * 8

typedef unsigned short u16;
typedef __attribute__((ext_vector_type(8))) short bf16x8;
typedef __attribute__((ext_vector_type(4))) float f32x4;

__device__ __forceinline__ short f2bfs(float f){
  __hip_bfloat16 h = __float2bfloat16(f);
  union { __hip_bfloat16 b; short u; } v; v.b = h; return v.u;
}
__device__ __forceinline__ unsigned int pack2(float lo, float hi){
  return (unsigned int)(u16)f2bfs(lo) | ((unsigned int)(u16)f2bfs(hi) << 16);
}
__device__ __forceinline__ float bfu(u16 u){
  union { unsigned int i; float f; } v; v.i = ((unsigned int)u) << 16; return v.f;
}
__device__ __forceinline__ float sigm(float x){ return 1.f / (1.f + __expf(-x)); }
__device__ __forceinline__ float tanh_fast(float x){
  float e = __expf(2.f * x);
  return 1.f - 2.f / (e + 1.f);
}
__device__ __forceinline__ float wred_max(float v){
  #pragma unroll
  for (int off = 32; off; off >>= 1) v = fmaxf(v, __shfl_xor(v, off, 64));
  return v;
}
__device__ __forceinline__ float wred_sum(float v){
  #pragma unroll
  for (int off = 32; off; off >>= 1) v += __shfl_xor(v, off, 64);
  return v;
}

// ---------------------------------------------------------------- init h0, x0
__global__ __launch_bounds__(256) void k_init(const float* __restrict__ eh,
                                              const float* __restrict__ semb,
                                              float* __restrict__ h_ws,
                                              float* __restrict__ x_ws)
{
  int idx = blockIdx.x * 256 + threadIdx.x;
  if (idx >= BSR * HH) return;
  int r = idx / HH, k = idx - r * HH;
  int batch = r % BB, slot = r / BB;       // row r = slot*B + batch
  h_ws[idx] = eh[batch * HH + k];
  x_ws[idx] = semb[slot * HH + k];
}

// ---- init-time split of x,h into hi/lo A-frags (rg layout) + h2 batch-major
__global__ __launch_bounds__(256) void k_split_xh(
    const float* __restrict__ h_ws, const float* __restrict__ x_ws,
    short* __restrict__ h_hi, short* __restrict__ h_lo,
    short* __restrict__ x_hi, short* __restrict__ x_lo,
    short* __restrict__ h2_hi, short* __restrict__ h2_lo)
{
  const int NU = NRT * NKK * 64;
  for (int u = blockIdx.x * 256 + threadIdx.x; u < 2 * NU; u += gridDim.x * 256){
    int uu = u; int sel = 0;
    if (uu >= NU){ uu -= NU; sel = 1; }
    const float* S = sel ? x_ws : h_ws;
    short* ph = sel ? x_hi : h_hi;
    short* pl = sel ? x_lo : h_lo;
    int lane = uu & 63, kt = uu >> 6;
    int rtile = kt / NKK, kk = kt - rtile * NKK;
    int lg = lane >> 4, rl = lane & 15;
    int r = rtile * 16 + rl, k = kk * 32 + lg * 8;
    bf16x8 oh, ol;
    #pragma unroll
    for (int j = 0; j < 8; ++j){
      if (k + j < HH){
        float v = S[(size_t)r * HH + k + j];
        short hb = f2bfs(v);
        oh[j] = hb; ol[j] = f2bfs(v - bfu((u16)hb));
      } else { oh[j] = 0; ol[j] = 0; }
    }
    *reinterpret_cast<bf16x8*>(ph + (size_t)uu * 8) = oh;
    *reinterpret_cast<bf16x8*>(pl + (size_t)uu * 8) = ol;
    if (!sel){
      // also batch-major copy for the scores GEMM: r = slot*16+batch
      int slot = r >> 4, batch = r & 15;
      size_t o2 = ((size_t)(batch * 2 + (slot >> 4)) * NKK + kk) * FRAG_STRIDE
                + (lg * 16 + (slot & 15)) * 8;
      *reinterpret_cast<bf16x8*>(h2_hi + o2) = oh;
      *reinterpret_cast<bf16x8*>(h2_lo + o2) = ol;
    }
  }
}

// ---- one-time: split W_ih, W_hh into hi/lo B-frags [75 ctile][13 kk][512]
__global__ __launch_bounds__(256) void k_cast_W(
    const float* __restrict__ Wih, const float* __restrict__ Whh,
    short* __restrict__ Wih_hi, short* __restrict__ Wih_lo,
    short* __restrict__ Whh_hi, short* __restrict__ Whh_lo)
{
  const int NU = NCT2 * NKK * 64;
  for (int u = blockIdx.x * 256 + threadIdx.x; u < 2 * NU; u += gridDim.x * 256){
    int uu = u; int sel = 0;
    if (uu >= NU){ uu -= NU; sel = 1; }
    const float* W = sel ? Whh : Wih;
    short* ph = sel ? Whh_hi : Wih_hi;
    short* pl = sel ? Whh_lo : Wih_lo;
    int lane = uu & 63, kt = uu >> 6;
    int ctile = kt / NKK, kk = kt - ctile * NKK;
    int lg = lane >> 4, cl = lane & 15;
    int c = ctile * 16 + cl, k = kk * 32 + lg * 8;
    bf16x8 oh, ol;
    #pragma unroll
    for (int j = 0; j < 8; ++j){
      if (k + j < HH){
        float v = W[(size_t)c * HH + k + j];
        short hb = f2bfs(v);
        oh[j] = hb; ol[j] = f2bfs(v - bfu((u16)hb));
      } else { oh[j] = 0; ol[j] = 0; }
    }
    *reinterpret_cast<bf16x8*>(ph + (size_t)uu * 8) = oh;
    *reinterpret_cast<bf16x8*>(pl + (size_t)uu * 8) = ol;
  }
}

// ---- one-time: emb f32[20000][400] -> bf16 MFMA-fragment layout
__global__ __launch_bounds__(256) void k_cast_emb(const float* __restrict__ emb,
                                                  short* __restrict__ ebf)
{
  const int nunit = NCT * NKK * 64;
  for (int u = blockIdx.x * 256 + threadIdx.x; u < nunit; u += gridDim.x * 256){
    int lane = u & 63;
    int kt = u >> 6;
    int ctile = kt / NKK, kk = kt - ctile * NKK;
    int lg = lane >> 4, cl = lane & 15;
    int c = ctile * 16 + cl;
    int k = kk * 32 + lg * 8;
    bf16x8 o;
    if (c < VV && k < HH){
      const float* src = emb + (size_t)c * HH + k;
      #pragma unroll
      for (int j = 0; j < 8; ++j) o[j] = f2bfs(src[j]);
    } else {
      #pragma unroll
      for (int j = 0; j < 8; ++j) o[j] = 0;
    }
    *reinterpret_cast<bf16x8*>(ebf + (size_t)u * 8) = o;
  }
}

// ---- one-time: enc f32[16][400][400] -> hi/lo B-frags for scores GEMM
// layout [b][stile 25][kk 13][512]: value enc[b][s=stile*16+cl][kh=kk*32+lg*8+j]
__global__ __launch_bounds__(256) void k_cast_encA(const float* __restrict__ enc,
                                                   short* __restrict__ eA_hi,
                                                   short* __restrict__ eA_lo)
{
  const int NU = BB * NST * NKK * 64;
  for (int u = blockIdx.x * 256 + threadIdx.x; u < NU; u += gridDim.x * 256){
    int lane = u & 63, kt = u >> 6;          // kt = (b*25+stile)*13 + kk
    int kk = kt % NKK; int ct = kt / NKK;
    int stile = ct % NST; int b = ct / NST;
    int lg = lane >> 4, cl = lane & 15;
    int s = stile * 16 + cl;
    int kh = kk * 32 + lg * 8;
    bf16x8 oh, ol;
    const float* src = enc + ((size_t)b * SS + s) * HH;
    #pragma unroll
    for (int j = 0; j < 8; ++j){
      if (kh + j < HH){
        float v = src[kh + j];
        short hb = f2bfs(v);
        oh[j] = hb; ol[j] = f2bfs(v - bfu((u16)hb));
      } else { oh[j] = 0; ol[j] = 0; }
    }
    *reinterpret_cast<bf16x8*>(eA_hi + (size_t)u * 8) = oh;
    *reinterpret_cast<bf16x8*>(eA_lo + (size_t)u * 8) = ol;
  }
}

// ---- gi = x*W_ih^T, gh = h*W_hh^T via split-bf16 MFMA (3 products, ~f32 acc).
__global__ __launch_bounds__(256) void k_gemm2_mfma(
    const short* __restrict__ x_hi, const short* __restrict__ x_lo,
    const short* __restrict__ h_hi, const short* __restrict__ h_lo,
    const short* __restrict__ Wih_hi, const short* __restrict__ Wih_lo,
    const short* __restrict__ Whh_hi, const short* __restrict__ Whh_lo,
    float* __restrict__ gi, float* __restrict__ gh)
{
  const int t = threadIdx.x;
  const int lane = t & 63, wid = t >> 6;
  const int wr = wid >> 1, wc = wid & 1;
  const int l15 = lane & 15, lg = lane >> 4;
  const int bM = blockIdx.x, bN = blockIdx.y, z = blockIdx.z;

  const short* A_hi = z ? h_hi : x_hi;
  const short* A_lo = z ? h_lo : x_lo;
  const short* B_hi = z ? Whh_hi : Wih_hi;
  const short* B_lo = z ? Whh_lo : Wih_lo;
  float* C = z ? gh : gi;

  const short *ah[4], *al[4], *bh[4], *bl[4];
  #pragma unroll
  for (int m = 0; m < 4; ++m){
    int rtile = min(bM * 8 + wr * 4 + m, NRT - 1);
    size_t off = (size_t)rtile * (NKK * FRAG_STRIDE) + lane * 8;
    ah[m] = A_hi + off; al[m] = A_lo + off;
  }
  #pragma unroll
  for (int n = 0; n < 4; ++n){
    int ctile = min(bN * 8 + wc * 4 + n, NCT2 - 1);
    size_t off = (size_t)ctile * (NKK * FRAG_STRIDE) + lane * 8;
    bh[n] = B_hi + off; bl[n] = B_lo + off;
  }

  f32x4 acc[4][4];
  #pragma unroll
  for (int m = 0; m < 4; ++m)
    #pragma unroll
    for (int n = 0; n < 4; ++n)
      acc[m][n] = (f32x4){0.f, 0.f, 0.f, 0.f};

  #pragma unroll
  for (int kk = 0; kk < NKK; ++kk){
    const int ko = kk * FRAG_STRIDE;
    bf16x8 ah_r[4], al_r[4];
    #pragma unroll
    for (int m = 0; m < 4; ++m){
      ah_r[m] = *reinterpret_cast<const bf16x8*>(ah[m] + ko);
      al_r[m] = *reinterpret_cast<const bf16x8*>(al[m] + ko);
    }
    #pragma unroll
    for (int n = 0; n < 4; ++n){
      bf16x8 bhv = *reinterpret_cast<const bf16x8*>(bh[n] + ko);
      bf16x8 blv = *reinterpret_cast<const bf16x8*>(bl[n] + ko);
      #pragma unroll
      for (int m = 0; m < 4; ++m){
        acc[m][n] = __builtin_amdgcn_mfma_f32_16x16x32_bf16(ah_r[m], bhv, acc[m][n], 0, 0, 0);
        acc[m][n] = __builtin_amdgcn_mfma_f32_16x16x32_bf16(ah_r[m], blv, acc[m][n], 0, 0, 0);
        acc[m][n] = __builtin_amdgcn_mfma_f32_16x16x32_bf16(al_r[m], bhv, acc[m][n], 0, 0, 0);
      }
    }
  }

  #pragma unroll
  for (int m = 0; m < 4; ++m){
    #pragma unroll
    for (int q = 0; q < 4; ++q){
      int row = bM * 128 + wr * 64 + m * 16 + lg * 4 + q;
      if (row < BSR){
        #pragma unroll
        for (int n = 0; n < 4; ++n){
          int col = bN * 128 + wc * 64 + n * 16 + l15;
          if (col < NG2) C[(size_t)row * NG2 + col] = acc[m][n][q];
        }
      }
    }
  }
}

// ---- per-row GRU: h_new from gi/gh; writes h_ws + frags in BOTH layouts
__global__ __launch_bounds__(128) void k_gru(
    const float* __restrict__ gi_ws, const float* __restrict__ gh_ws,
    const float* __restrict__ b_ih, const float* __restrict__ b_hh,
    float* __restrict__ h_ws,
    short* __restrict__ h_hi, short* __restrict__ h_lo,
    short* __restrict__ h2_hi, short* __restrict__ h2_lo)
{
  __shared__ float hn_s[HH];
  const int t = threadIdx.x;
  const int rg = blockIdx.x;
  const int slot = rg >> 4, batch = rg & 15;

  const float* gir = gi_ws + (size_t)rg * NG2;
  const float* ghr = gh_ws + (size_t)rg * NG2;
  for (int k = t; k < HH; k += 128){
    float irv = gir[k]          + b_ih[k];
    float izv = gir[HH + k]     + b_ih[HH + k];
    float inv = gir[2 * HH + k] + b_ih[2 * HH + k];
    float hrv = ghr[k]          + b_hh[k];
    float hzv = ghr[HH + k]     + b_hh[HH + k];
    float hnv = ghr[2 * HH + k] + b_hh[2 * HH + k];
    float rr = sigm(irv + hrv);
    float zz = sigm(izv + hzv);
    float nn = tanh_fast(inv + rr * hnv);
    float hold = h_ws[(size_t)rg * HH + k];
    float hnew = (1.f - zz) * nn + zz * hold;
    hn_s[k] = hnew;
    h_ws[(size_t)rg * HH + k] = hnew;
  }
  __syncthreads();

  if (t < KP / 8){                      // 52 units
    const int kk = t >> 2, lg = t & 3;
    bf16x8 oh, ol;
    #pragma unroll
    for (int j = 0; j < 8; ++j){
      int k = t * 8 + j;
      if (k < HH){
        float v = hn_s[k];
        short hb = f2bfs(v);
        oh[j] = hb; ol[j] = f2bfs(v - bfu((u16)hb));
      } else { oh[j] = 0; ol[j] = 0; }
    }
    size_t o1 = ((size_t)slot * NKK + kk) * FRAG_STRIDE + (lg * 16 + batch) * 8;
    *reinterpret_cast<bf16x8*>(h_hi + o1) = oh;
    *reinterpret_cast<bf16x8*>(h_lo + o1) = ol;
    size_t o2 = ((size_t)(batch * 2 + (slot >> 4)) * NKK + kk) * FRAG_STRIDE
              + (lg * 16 + (slot & 15)) * 8;
    *reinterpret_cast<bf16x8*>(h2_hi + o2) = oh;
    *reinterpret_cast<bf16x8*>(h2_lo + o2) = ol;
  }
}

// ---- scores[b][slot][s] = h_new . enc[b][s]  via split-bf16 MFMA (3 products)
// grid (16 b, 4 sc): 32 rows (slots, 2 padded) x 128 s-cols per block.
__global__ __launch_bounds__(256) void k_score(
    const short* __restrict__ h2_hi, const short* __restrict__ h2_lo,
    const short* __restrict__ eA_hi, const short* __restrict__ eA_lo,
    float* __restrict__ sc_ws)
{
  const int t = threadIdx.x;
  const int lane = t & 63, wid = t >> 6;
  const int wr = wid >> 1, wc = wid & 1;
  const int l15 = lane & 15, lg = lane >> 4;
  const int b = blockIdx.x, sc = blockIdx.y;

  const short *ah, *al;
  {
    size_t off = ((size_t)(b * 2 + wr) * NKK) * FRAG_STRIDE + lane * 8;
    ah = h2_hi + off; al = h2_lo + off;
  }
  const short *bh[4], *bl[4];
  #pragma unroll
  for (int n = 0; n < 4; ++n){
    int stile = min(sc * 8 + wc * 4 + n, NST - 1);
    size_t off = ((size_t)(b * NST + stile) * NKK) * FRAG_STRIDE + lane * 8;
    bh[n] = eA_hi + off; bl[n] = eA_lo + off;
  }

  f32x4 acc[4];
  #pragma unroll
  for (int n = 0; n < 4; ++n) acc[n] = (f32x4){0.f, 0.f, 0.f, 0.f};

  #pragma unroll
  for (int kk = 0; kk < NKK; ++kk){
    const int ko = kk * FRAG_STRIDE;
    bf16x8 ahv = *reinterpret_cast<const bf16x8*>(ah + ko);
    bf16x8 alv = *reinterpret_cast<const bf16x8*>(al + ko);
    #pragma unroll
    for (int n = 0; n < 4; ++n){
      bf16x8 bhv = *reinterpret_cast<const bf16x8*>(bh[n] + ko);
      bf16x8 blv = *reinterpret_cast<const bf16x8*>(bl[n] + ko);
      acc[n] = __builtin_amdgcn_mfma_f32_16x16x32_bf16(ahv, bhv, acc[n], 0, 0, 0);
      acc[n] = __builtin_amdgcn_mfma_f32_16x16x32_bf16(ahv, blv, acc[n], 0, 0, 0);
      acc[n] = __builtin_amdgcn_mfma_f32_16x16x32_bf16(alv, bhv, acc[n], 0, 0, 0);
    }
  }

  #pragma unroll
  for (int q = 0; q < 4; ++q){
    int slot = wr * 16 + lg * 4 + q;
    #pragma unroll
    for (int n = 0; n < 4; ++n){
      int s = sc * 128 + wc * 64 + n * 16 + l15;
      if (s < SS)
        sc_ws[((size_t)b * 32 + slot) * 512 + s] = acc[n][q];
    }
  }
}

// ----------- per-row: softmax(scores) -> prob, context (f32 enc, coalesced),
//             switch, gate (wi==0), teacher-forcing x update.
__global__ __launch_bounds__(256) void k_att2(
    const float* __restrict__ enc, const float* __restrict__ emb,
    const float* __restrict__ Wr_w, const float* __restrict__ Wr_b,
    const float* __restrict__ Wg_w, const float* __restrict__ Wg_b,
    const int* __restrict__ target, const int* __restrict__ lens,
    const float* __restrict__ sc_ws, const float* __restrict__ h_ws,
    float* __restrict__ x_ws,
    short* __restrict__ x_hi, short* __restrict__ x_lo,
    float* __restrict__ prob_ws, float* __restrict__ sw_ws,
    float* __restrict__ d_out, int wi)
{
  __shared__ float hn_s[HH];
  __shared__ float sc_s[SS];
  __shared__ float ctx_s[HH];
  __shared__ float red[4];
  __shared__ float redg[GG][4];

  const int t = threadIdx.x;
  const int rg = blockIdx.x;
  const int batch = rg % BB, slot = rg / BB;
  const int len = lens[batch];

  // stage h_new and scores
  for (int k = t; k < HH; k += 256) hn_s[k] = h_ws[(size_t)rg * HH + k];
  const float* scrow = sc_ws + ((size_t)batch * 32 + slot) * 512;
  float lmax = -3.0e38f;
  for (int s = t; s < SS; s += 256){
    float v = scrow[s];
    sc_s[s] = v;
    if (s < len) lmax = fmaxf(lmax, v);
  }
  lmax = wred_max(lmax);
  if ((t & 63) == 0) red[t >> 6] = lmax;
  __syncthreads();
  lmax = fmaxf(fmaxf(red[0], red[1]), fmaxf(red[2], red[3]));
  float lsum = 0.f;
  for (int s = t; s < SS; s += 256){
    float e = (s < len) ? __expf(sc_s[s] - lmax) : 0.f;
    sc_s[s] = e;
    lsum += e;
  }
  lsum = wred_sum(lsum);
  __syncthreads();
  if ((t & 63) == 0) red[t >> 6] = lsum;
  __syncthreads();
  lsum = red[0] + red[1] + red[2] + red[3];
  float invl = 1.f / lsum;
  for (int s = t; s < SS; s += 256){
    float p = sc_s[s] * invl;
    sc_s[s] = p;
    prob_ws[(size_t)rg * SS + s] = p;
  }
  __syncthreads();

  // context = prob @ enc  (coalesced: lanes sweep k at fixed s)
  const float* encb = enc + (size_t)batch * SS * HH;
  for (int k = t; k < HH; k += 256){
    float c0 = 0.f, c1 = 0.f, c2 = 0.f, c3 = 0.f;
    const float* ek = encb + k;
    int s = 0;
    for (; s + 3 < len; s += 4){
      c0 += sc_s[s]     * ek[(size_t)s * HH];
      c1 += sc_s[s + 1] * ek[(size_t)(s + 1) * HH];
      c2 += sc_s[s + 2] * ek[(size_t)(s + 2) * HH];
      c3 += sc_s[s + 3] * ek[(size_t)(s + 3) * HH];
    }
    for (; s < len; ++s) c0 += sc_s[s] * ek[(size_t)s * HH];
    ctx_s[k] = (c0 + c1) + (c2 + c3);
  }
  __syncthreads();

  float sa = 0.f;
  for (int k = t; k < HH; k += 256){
    sa += Wr_w[k]          * hn_s[k]
        + Wr_w[HH + k]     * ctx_s[k]
        + Wr_w[2 * HH + k] * x_ws[(size_t)rg * HH + k];
  }
  sa = wred_sum(sa);
  if ((t & 63) == 0) red[t >> 6] = sa;
  __syncthreads();
  sa = red[0] + red[1] + red[2] + red[3];
  if (t == 0) sw_ws[rg] = sigm(sa + Wr_b[0]);

  if (wi == 0){
    float ga[GG] = {0.f, 0.f, 0.f};
    for (int k = t; k < HH; k += 256){
      float cv = ctx_s[k];
      ga[0] += Wg_w[k] * cv;
      ga[1] += Wg_w[HH + k] * cv;
      ga[2] += Wg_w[2 * HH + k] * cv;
    }
    #pragma unroll
    for (int g = 0; g < GG; ++g){
      ga[g] = wred_sum(ga[g]);
      if ((t & 63) == 0) redg[g][t >> 6] = ga[g];
    }
    __syncthreads();
    if (t < GG)
      d_out[(size_t)NSLOT * BB * TT * VV + (size_t)rg * GG + t] =
          redg[t][0] + redg[t][1] + redg[t][2] + redg[t][3] + Wg_b[t];
  }

  // x <- emb[target] (next step's input): f32 row + hi/lo A-frags
  const int tgt = target[batch * (NSLOT * TT) + slot * TT + wi];
  const float* embrow = emb + (size_t)tgt * HH;
  for (int k = t; k < HH; k += 256)
    x_ws[(size_t)rg * HH + k] = embrow[k];
  if (t < KP / 8){
    const int kk = t >> 2, lg = t & 3;
    bf16x8 oh, ol;
    #pragma unroll
    for (int j = 0; j < 8; ++j){
      int k = t * 8 + j;
      if (k < HH){
        float v = embrow[k];
        short hb = f2bfs(v);
        oh[j] = hb; ol[j] = f2bfs(v - bfu((u16)hb));
      } else { oh[j] = 0; ol[j] = 0; }
    }
    size_t off = ((size_t)slot * NKK + kk) * FRAG_STRIDE + (lg * 16 + batch) * 8;
    *reinterpret_cast<bf16x8*>(x_hi + off) = oh;
    *reinterpret_cast<bf16x8*>(x_lo + off) = ol;
  }
}

// --------- logits = h x emb^T via MFMA bf16, 128x128 block tile.
__global__ __launch_bounds__(256) void k_logits_mfma(
    const short* __restrict__ hbf, const short* __restrict__ ebf,
    float* __restrict__ out, float* __restrict__ pmax_ws,
    float* __restrict__ psum_ws, int wi)
{
  const int t = threadIdx.x;
  const int lane = t & 63, wid = t >> 6;
  const int wr = wid >> 1, wc = wid & 1;
  const int l15 = lane & 15, lg = lane >> 4;
  const int bM = blockIdx.x, bN = blockIdx.y;

  const short* ap[4];
  const short* bp[4];
  #pragma unroll
  for (int m = 0; m < 4; ++m){
    int rtile = bM * 8 + wr * 4 + m;
    ap[m] = hbf + (size_t)min(rtile, NRT - 1) * (NKK * FRAG_STRIDE) + lane * 8;
  }
  #pragma unroll
  for (int n = 0; n < 4; ++n){
    int ctile = bN * 8 + wc * 4 + n;
    bp[n] = ebf + (size_t)ctile * (NKK * FRAG_STRIDE) + lane * 8;
  }

  f32x4 acc[4][4];
  #pragma unroll
  for (int m = 0; m < 4; ++m)
    #pragma unroll
    for (int n = 0; n < 4; ++n)
      acc[m][n] = (f32x4){0.f, 0.f, 0.f, 0.f};

  #pragma unroll
  for (int kk = 0; kk < NKK; ++kk){
    const int ko = kk * FRAG_STRIDE;
    bf16x8 a[4];
    #pragma unroll
    for (int m = 0; m < 4; ++m)
      a[m] = *reinterpret_cast<const bf16x8*>(ap[m] + ko);
    #pragma unroll
    for (int n = 0; n < 4; ++n){
      bf16x8 b = *reinterpret_cast<const bf16x8*>(bp[n] + ko);
      #pragma unroll
      for (int m = 0; m < 4; ++m)
        acc[m][n] = __builtin_amdgcn_mfma_f32_16x16x32_bf16(a[m], b, acc[m][n], 0, 0, 0);
    }
  }

  #pragma unroll
  for (int m = 0; m < 4; ++m){
    #pragma unroll
    for (int q = 0; q < 4; ++q){
      int row = bM * 128 + wr * 64 + m * 16 + lg * 4 + q;
      u16* lrow16 = reinterpret_cast<u16*>(out + ((size_t)row * TT + wi) * VV);
      #pragma unroll
      for (int n = 0; n < 4; ++n){
        float v = acc[m][n][q];
        float vp = __shfl_xor(v, 1, 64);
        int col = bN * 128 + wc * 64 + n * 16 + l15;
        if (((l15 & 1) == 0) && row < BSR && col < VV)
          *reinterpret_cast<unsigned int*>(lrow16 + col) = pack2(v, vp);
      }
    }
    f32x4 rmax, rsum;
    #pragma unroll
    for (int q = 0; q < 4; ++q){
      float mx = -3.0e38f;
      #pragma unroll
      for (int n = 0; n < 4; ++n){
        int col = bN * 128 + wc * 64 + n * 16 + l15;
        float v = (col < VV) ? acc[m][n][q] : -3.0e38f;
        mx = fmaxf(mx, v);
      }
      #pragma unroll
      for (int off = 1; off < 16; off <<= 1) mx = fmaxf(mx, __shfl_xor(mx, off, 64));
      float sm = 0.f;
      #pragma unroll
      for (int n = 0; n < 4; ++n){
        int col = bN * 128 + wc * 64 + n * 16 + l15;
        if (col < VV) sm += __expf(acc[m][n][q] - mx);
      }
      #pragma unroll
      for (int off = 1; off < 16; off <<= 1) sm += __shfl_xor(sm, off, 64);
      rmax[q] = mx; rsum[q] = sm;
    }
    if (l15 == 0){
      #pragma unroll
      for (int q = 0; q < 4; ++q){
        int row = bM * 128 + wr * 64 + m * 16 + lg * 4 + q;
        if (row < BSR){
          size_t pidx = ((size_t)row * NBN + bN) * 2 + wc;
          pmax_ws[pidx] = rmax[q];
          psum_ws[pidx] = rsum[q];
        }
      }
    }
  }
}

// ---- combine partials + pointer mix; expand bf16 logits (in d_out, via LDS)
//      to f32 final distribution IN PLACE. One block per row.
__global__ __launch_bounds__(256) void k_finalize(
    float* __restrict__ logits_out, const float* __restrict__ prob_ws,
    const float* __restrict__ pmax_ws, const float* __restrict__ psum_ws,
    const float* __restrict__ sw_ws, const int* __restrict__ story,
    const int* __restrict__ lens, int wi)
{
  __shared__ float pctx[VV];          // 80 KB
  __shared__ u16 rowbuf[VV];          // 40 KB bf16 logit row
  __shared__ float red[4];
  const int t = threadIdx.x;
  const int r = blockIdx.x;
  const int batch = r % BB;
  for (int v = t; v < VV; v += 256) pctx[v] = 0.f;
  __syncthreads();
  const int len = lens[batch];
  for (int s = t; s < SS; s += 256){
    if (s < len)
      atomicAdd(&pctx[story[batch * SS + s]], prob_ws[(size_t)r * SS + s]);
  }

  float* lrow = logits_out + ((size_t)r * TT + wi) * VV;
  const uint4* l16 = reinterpret_cast<const uint4*>(lrow);
  for (int i = t; i < VV / 8; i += 256)
    reinterpret_cast<uint4*>(rowbuf)[i] = l16[i];

  const float* pm = pmax_ws + (size_t)r * (NBN * 2);
  const float* ps = psum_ws + (size_t)r * (NBN * 2);
  float m = -3.0e38f;
  for (int i = t; i < NBN * 2; i += 256) m = fmaxf(m, pm[i]);
  m = wred_max(m);
  if ((t & 63) == 0) red[t >> 6] = m;
  __syncthreads();
  m = fmaxf(fmaxf(red[0], red[1]), fmaxf(red[2], red[3]));
  float lsum = 0.f;
  for (int i = t; i < NBN * 2; i += 256) lsum += ps[i] * __expf(pm[i] - m);
  lsum = wred_sum(lsum);
  __syncthreads();
  if ((t & 63) == 0) red[t >> 6] = lsum;
  __syncthreads();
  lsum = red[0] + red[1] + red[2] + red[3];

  const float sw = sw_ws[r];
  const float invl = sw / lsum;
  const float osw = 1.f - sw;
  float4* o4 = reinterpret_cast<float4*>(lrow);
  for (int i = t; i < VV / 4; i += 256){
    ushort4 s4 = reinterpret_cast<const ushort4*>(rowbuf)[i];
    int v = i * 4;
    float4 o;
    o.x = __expf(bfu(s4.x) - m) * invl + osw * pctx[v + 0];
    o.y = __expf(bfu(s4.y) - m) * invl + osw * pctx[v + 1];
    o.z = __expf(bfu(s4.z) - m) * invl + osw * pctx[v + 2];
    o.w = __expf(bfu(s4.w) - m) * invl + osw * pctx[v + 3];
    o4[i] = o;
  }
}

extern "C" void kernel_launch(void* const* d_in, const int* in_sizes, int n_in,
                              void* d_out, int out_size, void* d_ws, size_t ws_size,
                              hipStream_t stream)
{
  (void)in_sizes; (void)n_in; (void)out_size; (void)ws_size;
  const float* eh    = (const float*)d_in[0];
  const float* enc   = (const float*)d_in[1];
  const float* semb  = (const float*)d_in[2];
  const float* emb   = (const float*)d_in[3];
  const float* W_ih  = (const float*)d_in[4];
  const float* W_hh  = (const float*)d_in[5];
  const float* b_ih  = (const float*)d_in[6];
  const float* b_hh  = (const float*)d_in[7];
  const float* Wr_w  = (const float*)d_in[8];
  const float* Wr_b  = (const float*)d_in[9];
  const float* Wg_w  = (const float*)d_in[10];
  const float* Wg_b  = (const float*)d_in[11];
  const int* story = (const int*)d_in[12];
  const int* tgt   = (const int*)d_in[13];
  const int* lens  = (const int*)d_in[14];
  float* out = (float*)d_out;

  // ws layout (f32 offsets); total ~41.9 MB (evidence: ws >= 45.3 MB, round 2)
  float* ws      = (float*)d_ws;
  float* h_ws    = ws;                        // 192000
  float* x_ws    = ws + 192000;               // 192000
  float* prob_ws = ws + 384000;               // 192000
  float* sw_ws   = ws + 576000;               // 512
  float* gi_ws   = ws + 576512;               // 576000
  float* gh_ws   = ws + 1152512;              // 576000
  float* pmax_ws = ws + 1728512;              // 151040
  float* psum_ws = ws + 1879552;              // 151040
  short* h_hi    = (short*)(ws + 2030592);    // 30*13*512 shorts (99840 f32)
  short* emb_bf  = (short*)(ws + 2130432);    // 1256*13*512 shorts (4179968 f32)
  short* Wih_hi  = (short*)(ws + 6310400);    // 75*13*512 shorts (249600 f32)
  short* Wih_lo  = (short*)(ws + 6560000);
  short* Whh_hi  = (short*)(ws + 6809600);
  short* Whh_lo  = (short*)(ws + 7059200);
  short* x_hi    = (short*)(ws + 7308800);    // 99840 f32 each
  short* x_lo    = (short*)(ws + 7408640);
  short* h_lo    = (short*)(ws + 7508480);
  short* h2_hi   = (short*)(ws + 7608320);    // 32*13*512 shorts (106496 f32)
  short* h2_lo   = (short*)(ws + 7714816);    // 106496
  short* eA_hi   = (short*)(ws + 7821312);    // 16*25*13*512 shorts (1331200 f32)
  short* eA_lo   = (short*)(ws + 9152512);    // 1331200; ends 10483712
  float* sc_ws   = gi_ws;                     // alias: gi consumed by k_gru
                                              // before k_score writes, re-made
                                              // by next step's k_gemm2

  k_cast_emb<<<2048, 256, 0, stream>>>(emb, emb_bf);
  k_cast_W<<<512, 256, 0, stream>>>(W_ih, W_hh, Wih_hi, Wih_lo, Whh_hi, Whh_lo);
  k_cast_encA<<<1024, 256, 0, stream>>>(enc, eA_hi, eA_lo);
  k_init<<<750, 256, 0, stream>>>(eh, semb, h_ws, x_ws);
  k_split_xh<<<195, 256, 0, stream>>>(h_ws, x_ws, h_hi, h_lo, x_hi, x_lo,
                                      h2_hi, h2_lo);
  for (int wi = 0; wi < TT; ++wi){
    dim3 gg(4, 10, 2);
    k_gemm2_mfma<<<gg, 256, 0, stream>>>(x_hi, x_lo, h_hi, h_lo,
                                         Wih_hi, Wih_lo, Whh_hi, Whh_lo,
                                         gi_ws, gh_ws);
    k_gru<<<BSR, 128, 0, stream>>>(gi_ws, gh_ws, b_ih, b_hh, h_ws,
                                   h_hi, h_lo, h2_hi, h2_lo);
    dim3 gs(16, 4);
    k_score<<<gs, 256, 0, stream>>>(h2_hi, h2_lo, eA_hi, eA_lo, sc_ws);
    k_att2<<<BSR, 256, 0, stream>>>(enc, emb, Wr_w, Wr_b, Wg_w, Wg_b,
                                    tgt, lens, sc_ws, h_ws, x_ws,
                                    x_hi, x_lo, prob_ws, sw_ws, out, wi);
    dim3 gl(4, NBN);
    k_logits_mfma<<<gl, 256, 0, stream>>>(h_hi, emb_bf, out, pmax_ws, psum_ws, wi);
    k_finalize<<<BSR, 256, 0, stream>>>(out, prob_ws, pmax_ws, psum_ws,
                                        sw_ws, story, lens, wi);
  }
}

// Round 12
// 997.743 us; speedup vs baseline: 1.1446x; 1.1446x over previous
//
#include <hip/hip_runtime.h>
#include <hip/hip_bf16.h>

#define NSLOT 30
#define BB    16
#define TT    8
#define SS    400
#define HH    400
#define KP    416           // K padded to 13*32 for MFMA
#define NKK   13            // KP/32
#define VV    20000
#define GG    3
#define BSR   480           // NSLOT*BB fused decode rows
#define NBN   157           // ceil(VV/128) col-blocks
#define NCT   1256          // NBN*8 col tiles in emb frag buffer (zero-padded)
#define NG2   1200          // gemm2 output cols (3*HH)
#define NCT2  75            // NG2/16 col tiles for W frags
#define NRT   30            // BSR/16 row tiles
#define FRAG_STRIDE 512     // shorts per (tile,kk): 64 lanes * 8

typedef unsigned short u16;
typedef __attribute__((ext_vector_type(8))) short bf16x8;
typedef __attribute__((ext_vector_type(4))) float f32x4;

__device__ __forceinline__ short f2bfs(float f){
  __hip_bfloat16 h = __float2bfloat16(f);
  union { __hip_bfloat16 b; short u; } v; v.b = h; return v.u;
}
__device__ __forceinline__ unsigned int pack2(float lo, float hi){
  return (unsigned int)(u16)f2bfs(lo) | ((unsigned int)(u16)f2bfs(hi) << 16);
}
__device__ __forceinline__ float bfu(u16 u){
  union { unsigned int i; float f; } v; v.i = ((unsigned int)u) << 16; return v.f;
}
__device__ __forceinline__ float bfu_lo(unsigned int u){
  union { unsigned int i; float f; } v; v.i = u << 16; return v.f;
}
__device__ __forceinline__ float bfu_hi(unsigned int u){
  union { unsigned int i; float f; } v; v.i = u & 0xffff0000u; return v.f;
}
__device__ __forceinline__ float sigm(float x){ return 1.f / (1.f + __expf(-x)); }
__device__ __forceinline__ float tanh_fast(float x){
  float e = __expf(2.f * x);
  return 1.f - 2.f / (e + 1.f);
}
__device__ __forceinline__ float wred_max(float v){
  #pragma unroll
  for (int off = 32; off; off >>= 1) v = fmaxf(v, __shfl_xor(v, off, 64));
  return v;
}
__device__ __forceinline__ float wred_sum(float v){
  #pragma unroll
  for (int off = 32; off; off >>= 1) v += __shfl_xor(v, off, 64);
  return v;
}

// ---------------------------------------------------------------- init h0, x0
__global__ __launch_bounds__(256) void k_init(const float* __restrict__ eh,
                                              const float* __restrict__ semb,
                                              float* __restrict__ h_ws,
                                              float* __restrict__ x_ws)
{
  int idx = blockIdx.x * 256 + threadIdx.x;
  if (idx >= BSR * HH) return;
  int r = idx / HH, k = idx - r * HH;
  int batch = r % BB, slot = r / BB;       // row r = slot*B + batch
  h_ws[idx] = eh[batch * HH + k];
  x_ws[idx] = semb[slot * HH + k];
}

// ---- init-time split of x,h into hi/lo A-frags
__global__ __launch_bounds__(256) void k_split_xh(
    const float* __restrict__ h_ws, const float* __restrict__ x_ws,
    short* __restrict__ h_hi, short* __restrict__ h_lo,
    short* __restrict__ x_hi, short* __restrict__ x_lo)
{
  const int NU = NRT * NKK * 64;
  for (int u = blockIdx.x * 256 + threadIdx.x; u < 2 * NU; u += gridDim.x * 256){
    int uu = u; int sel = 0;
    if (uu >= NU){ uu -= NU; sel = 1; }
    const float* S = sel ? x_ws : h_ws;
    short* ph = sel ? x_hi : h_hi;
    short* pl = sel ? x_lo : h_lo;
    int lane = uu & 63, kt = uu >> 6;
    int rtile = kt / NKK, kk = kt - rtile * NKK;
    int lg = lane >> 4, rl = lane & 15;
    int r = rtile * 16 + rl, k = kk * 32 + lg * 8;
    bf16x8 oh, ol;
    #pragma unroll
    for (int j = 0; j < 8; ++j){
      if (k + j < HH){
        float v = S[(size_t)r * HH + k + j];
        short hb = f2bfs(v);
        oh[j] = hb; ol[j] = f2bfs(v - bfu((u16)hb));
      } else { oh[j] = 0; ol[j] = 0; }
    }
    *reinterpret_cast<bf16x8*>(ph + (size_t)uu * 8) = oh;
    *reinterpret_cast<bf16x8*>(pl + (size_t)uu * 8) = ol;
  }
}

// ---- one-time: split W_ih, W_hh into hi/lo B-frags [75 ctile][13 kk][512]
__global__ __launch_bounds__(256) void k_cast_W(
    const float* __restrict__ Wih, const float* __restrict__ Whh,
    short* __restrict__ Wih_hi, short* __restrict__ Wih_lo,
    short* __restrict__ Whh_hi, short* __restrict__ Whh_lo)
{
  const int NU = NCT2 * NKK * 64;
  for (int u = blockIdx.x * 256 + threadIdx.x; u < 2 * NU; u += gridDim.x * 256){
    int uu = u; int sel = 0;
    if (uu >= NU){ uu -= NU; sel = 1; }
    const float* W = sel ? Whh : Wih;
    short* ph = sel ? Whh_hi : Wih_hi;
    short* pl = sel ? Whh_lo : Wih_lo;
    int lane = uu & 63, kt = uu >> 6;
    int ctile = kt / NKK, kk = kt - ctile * NKK;
    int lg = lane >> 4, cl = lane & 15;
    int c = ctile * 16 + cl, k = kk * 32 + lg * 8;
    bf16x8 oh, ol;
    #pragma unroll
    for (int j = 0; j < 8; ++j){
      if (k + j < HH){
        float v = W[(size_t)c * HH + k + j];
        short hb = f2bfs(v);
        oh[j] = hb; ol[j] = f2bfs(v - bfu((u16)hb));
      } else { oh[j] = 0; ol[j] = 0; }
    }
    *reinterpret_cast<bf16x8*>(ph + (size_t)uu * 8) = oh;
    *reinterpret_cast<bf16x8*>(pl + (size_t)uu * 8) = ol;
  }
}

// ---- one-time: emb f32[20000][400] -> bf16 MFMA-fragment layout
__global__ __launch_bounds__(256) void k_cast_emb(const float* __restrict__ emb,
                                                  short* __restrict__ ebf)
{
  const int nunit = NCT * NKK * 64;
  for (int u = blockIdx.x * 256 + threadIdx.x; u < nunit; u += gridDim.x * 256){
    int lane = u & 63;
    int kt = u >> 6;
    int ctile = kt / NKK, kk = kt - ctile * NKK;
    int lg = lane >> 4, cl = lane & 15;
    int c = ctile * 16 + cl;
    int k = kk * 32 + lg * 8;
    bf16x8 o;
    if (c < VV && k < HH){
      const float* src = emb + (size_t)c * HH + k;
      #pragma unroll
      for (int j = 0; j < 8; ++j) o[j] = f2bfs(src[j]);
    } else {
      #pragma unroll
      for (int j = 0; j < 8; ++j) o[j] = 0;
    }
    *reinterpret_cast<bf16x8*>(ebf + (size_t)u * 8) = o;
  }
}

// ---- gi = x*W_ih^T, gh = h*W_hh^T via split-bf16 MFMA (3 products, ~f32 acc).
__global__ __launch_bounds__(256) void k_gemm2_mfma(
    const short* __restrict__ x_hi, const short* __restrict__ x_lo,
    const short* __restrict__ h_hi, const short* __restrict__ h_lo,
    const short* __restrict__ Wih_hi, const short* __restrict__ Wih_lo,
    const short* __restrict__ Whh_hi, const short* __restrict__ Whh_lo,
    float* __restrict__ gi, float* __restrict__ gh)
{
  const int t = threadIdx.x;
  const int lane = t & 63, wid = t >> 6;
  const int wr = wid >> 1, wc = wid & 1;
  const int l15 = lane & 15, lg = lane >> 4;
  const int bM = blockIdx.x, bN = blockIdx.y, z = blockIdx.z;

  const short* A_hi = z ? h_hi : x_hi;
  const short* A_lo = z ? h_lo : x_lo;
  const short* B_hi = z ? Whh_hi : Wih_hi;
  const short* B_lo = z ? Whh_lo : Wih_lo;
  float* C = z ? gh : gi;

  const short *ah[4], *al[4], *bh[4], *bl[4];
  #pragma unroll
  for (int m = 0; m < 4; ++m){
    int rtile = min(bM * 8 + wr * 4 + m, NRT - 1);
    size_t off = (size_t)rtile * (NKK * FRAG_STRIDE) + lane * 8;
    ah[m] = A_hi + off; al[m] = A_lo + off;
  }
  #pragma unroll
  for (int n = 0; n < 4; ++n){
    int ctile = min(bN * 8 + wc * 4 + n, NCT2 - 1);
    size_t off = (size_t)ctile * (NKK * FRAG_STRIDE) + lane * 8;
    bh[n] = B_hi + off; bl[n] = B_lo + off;
  }

  f32x4 acc[4][4];
  #pragma unroll
  for (int m = 0; m < 4; ++m)
    #pragma unroll
    for (int n = 0; n < 4; ++n)
      acc[m][n] = (f32x4){0.f, 0.f, 0.f, 0.f};

  #pragma unroll
  for (int kk = 0; kk < NKK; ++kk){
    const int ko = kk * FRAG_STRIDE;
    bf16x8 ah_r[4], al_r[4];
    #pragma unroll
    for (int m = 0; m < 4; ++m){
      ah_r[m] = *reinterpret_cast<const bf16x8*>(ah[m] + ko);
      al_r[m] = *reinterpret_cast<const bf16x8*>(al[m] + ko);
    }
    #pragma unroll
    for (int n = 0; n < 4; ++n){
      bf16x8 bhv = *reinterpret_cast<const bf16x8*>(bh[n] + ko);
      bf16x8 blv = *reinterpret_cast<const bf16x8*>(bl[n] + ko);
      #pragma unroll
      for (int m = 0; m < 4; ++m){
        acc[m][n] = __builtin_amdgcn_mfma_f32_16x16x32_bf16(ah_r[m], bhv, acc[m][n], 0, 0, 0);
        acc[m][n] = __builtin_amdgcn_mfma_f32_16x16x32_bf16(ah_r[m], blv, acc[m][n], 0, 0, 0);
        acc[m][n] = __builtin_amdgcn_mfma_f32_16x16x32_bf16(al_r[m], bhv, acc[m][n], 0, 0, 0);
      }
    }
  }

  #pragma unroll
  for (int m = 0; m < 4; ++m){
    #pragma unroll
    for (int q = 0; q < 4; ++q){
      int row = bM * 128 + wr * 64 + m * 16 + lg * 4 + q;
      if (row < BSR){
        #pragma unroll
        for (int n = 0; n < 4; ++n){
          int col = bN * 128 + wc * 64 + n * 16 + l15;
          if (col < NG2) C[(size_t)row * NG2 + col] = acc[m][n][q];
        }
      }
    }
  }
}

// --------- logits = h x emb^T via MFMA bf16, 128x128 block tile.
// Writes bf16 logits packed into the FIRST HALF of each f32 out row (in place),
// plus per-(row, bN, wave-half) partial max + sumexp.
__global__ __launch_bounds__(256) void k_logits_mfma(
    const short* __restrict__ hbf, const short* __restrict__ ebf,
    float* __restrict__ out, float* __restrict__ pmax_ws,
    float* __restrict__ psum_ws, int wi)
{
  const int t = threadIdx.x;
  const int lane = t & 63, wid = t >> 6;
  const int wr = wid >> 1, wc = wid & 1;
  const int l15 = lane & 15, lg = lane >> 4;
  const int bM = blockIdx.x, bN = blockIdx.y;

  const short* ap[4];
  const short* bp[4];
  #pragma unroll
  for (int m = 0; m < 4; ++m){
    int rtile = bM * 8 + wr * 4 + m;
    ap[m] = hbf + (size_t)min(rtile, NRT - 1) * (NKK * FRAG_STRIDE) + lane * 8;
  }
  #pragma unroll
  for (int n = 0; n < 4; ++n){
    int ctile = bN * 8 + wc * 4 + n;
    bp[n] = ebf + (size_t)ctile * (NKK * FRAG_STRIDE) + lane * 8;
  }

  f32x4 acc[4][4];
  #pragma unroll
  for (int m = 0; m < 4; ++m)
    #pragma unroll
    for (int n = 0; n < 4; ++n)
      acc[m][n] = (f32x4){0.f, 0.f, 0.f, 0.f};

  #pragma unroll
  for (int kk = 0; kk < NKK; ++kk){
    const int ko = kk * FRAG_STRIDE;
    bf16x8 a[4];
    #pragma unroll
    for (int m = 0; m < 4; ++m)
      a[m] = *reinterpret_cast<const bf16x8*>(ap[m] + ko);
    #pragma unroll
    for (int n = 0; n < 4; ++n){
      bf16x8 b = *reinterpret_cast<const bf16x8*>(bp[n] + ko);
      #pragma unroll
      for (int m = 0; m < 4; ++m)
        acc[m][n] = __builtin_amdgcn_mfma_f32_16x16x32_bf16(a[m], b, acc[m][n], 0, 0, 0);
    }
  }

  #pragma unroll
  for (int m = 0; m < 4; ++m){
    #pragma unroll
    for (int q = 0; q < 4; ++q){
      int row = bM * 128 + wr * 64 + m * 16 + lg * 4 + q;
      u16* lrow16 = reinterpret_cast<u16*>(out + ((size_t)row * TT + wi) * VV);
      #pragma unroll
      for (int n = 0; n < 4; ++n){
        float v = acc[m][n][q];
        float vp = __shfl_xor(v, 1, 64);
        int col = bN * 128 + wc * 64 + n * 16 + l15;
        if (((l15 & 1) == 0) && row < BSR && col < VV)
          *reinterpret_cast<unsigned int*>(lrow16 + col) = pack2(v, vp);
      }
    }
    f32x4 rmax, rsum;
    #pragma unroll
    for (int q = 0; q < 4; ++q){
      float mx = -3.0e38f;
      #pragma unroll
      for (int n = 0; n < 4; ++n){
        int col = bN * 128 + wc * 64 + n * 16 + l15;
        float v = (col < VV) ? acc[m][n][q] : -3.0e38f;
        mx = fmaxf(mx, v);
      }
      #pragma unroll
      for (int off = 1; off < 16; off <<= 1) mx = fmaxf(mx, __shfl_xor(mx, off, 64));
      float sm = 0.f;
      #pragma unroll
      for (int n = 0; n < 4; ++n){
        int col = bN * 128 + wc * 64 + n * 16 + l15;
        if (col < VV) sm += __expf(acc[m][n][q] - mx);
      }
      #pragma unroll
      for (int off = 1; off < 16; off <<= 1) sm += __shfl_xor(sm, off, 64);
      rmax[q] = mx; rsum[q] = sm;
    }
    if (l15 == 0){
      #pragma unroll
      for (int q = 0; q < 4; ++q){
        int row = bM * 128 + wr * 64 + m * 16 + lg * 4 + q;
        if (row < BSR){
          size_t pidx = ((size_t)row * NBN + bN) * 2 + wc;
          pmax_ws[pidx] = rmax[q];
          psum_ws[pidx] = rsum[q];
        }
      }
    }
  }
}

// ----------- per-row: GRU gates -> h_new (+hi/lo frag), attention, softmax,
//             context, switch, gate (wi==0), teacher-forcing x (+hi/lo frag).
__global__ __launch_bounds__(256) void k_att(
    const float* __restrict__ enc, const float* __restrict__ emb,
    const float* __restrict__ b_ih, const float* __restrict__ b_hh,
    const float* __restrict__ Wr_w, const float* __restrict__ Wr_b,
    const float* __restrict__ Wg_w, const float* __restrict__ Wg_b,
    const int* __restrict__ target, const int* __restrict__ lens,
    const float* __restrict__ gi_ws, const float* __restrict__ gh_ws,
    float* __restrict__ h_ws, float* __restrict__ x_ws,
    short* __restrict__ h_hi, short* __restrict__ h_lo,
    short* __restrict__ x_hi, short* __restrict__ x_lo,
    float* __restrict__ prob_ws, float* __restrict__ sw_ws,
    float* __restrict__ d_out, int wi)
{
  __shared__ float hn_s[HH];
  __shared__ float sc_s[SS];
  __shared__ float ctx_s[HH];
  __shared__ float red[4];
  __shared__ float redg[GG][4];

  const int t = threadIdx.x;
  const int rg = blockIdx.x;
  const int batch = rg % BB, slot = rg / BB;
  const int len = lens[batch];
  const int rtile = rg >> 4, rl = rg & 15;

  // GRU gates -> h_new
  const float* gir = gi_ws + (size_t)rg * NG2;
  const float* ghr = gh_ws + (size_t)rg * NG2;
  for (int k = t; k < HH; k += 256){
    float irv = gir[k]          + b_ih[k];
    float izv = gir[HH + k]     + b_ih[HH + k];
    float inv = gir[2 * HH + k] + b_ih[2 * HH + k];
    float hrv = ghr[k]          + b_hh[k];
    float hzv = ghr[HH + k]     + b_hh[HH + k];
    float hnv = ghr[2 * HH + k] + b_hh[2 * HH + k];
    float rr = sigm(irv + hrv);
    float zz = sigm(izv + hzv);
    float nn = tanh_fast(inv + rr * hnv);
    float hold = h_ws[(size_t)rg * HH + k];
    float hnew = (1.f - zz) * nn + zz * hold;
    hn_s[k] = hnew;
    h_ws[(size_t)rg * HH + k] = hnew;
  }
  __syncthreads();

  // h_new -> hi/lo A-frags
  if (t < KP / 8){                      // 52 units
    const int kk = t >> 2, lg = t & 3;
    bf16x8 oh, ol;
    #pragma unroll
    for (int j = 0; j < 8; ++j){
      int k = t * 8 + j;
      if (k < HH){
        float v = hn_s[k];
        short hb = f2bfs(v);
        oh[j] = hb; ol[j] = f2bfs(v - bfu((u16)hb));
      } else { oh[j] = 0; ol[j] = 0; }
    }
    size_t off = ((size_t)rtile * NKK + kk) * FRAG_STRIDE + (lg * 16 + rl) * 8;
    *reinterpret_cast<bf16x8*>(h_hi + off) = oh;
    *reinterpret_cast<bf16x8*>(h_lo + off) = ol;
  }

  const float* encb = enc + (size_t)batch * SS * HH;
  float lmax = -3.0e38f;
  for (int s = t; s < SS; s += 256){
    if (s < len){
      const float4* er4 = reinterpret_cast<const float4*>(encb + (size_t)s * HH);
      float dot = 0.f;
      for (int k4 = 0; k4 < HH / 4; ++k4){
        float4 e = er4[k4];
        float4 hv = *reinterpret_cast<const float4*>(&hn_s[k4 * 4]);
        dot += e.x*hv.x + e.y*hv.y + e.z*hv.z + e.w*hv.w;
      }
      sc_s[s] = dot;
      lmax = fmaxf(lmax, dot);
    }
  }
  lmax = wred_max(lmax);
  if ((t & 63) == 0) red[t >> 6] = lmax;
  __syncthreads();
  lmax = fmaxf(fmaxf(red[0], red[1]), fmaxf(red[2], red[3]));
  float lsum = 0.f;
  for (int s = t; s < SS; s += 256){
    float e = (s < len) ? __expf(sc_s[s] - lmax) : 0.f;
    sc_s[s] = e;
    lsum += e;
  }
  lsum = wred_sum(lsum);
  __syncthreads();
  if ((t & 63) == 0) red[t >> 6] = lsum;
  __syncthreads();
  lsum = red[0] + red[1] + red[2] + red[3];
  float invl = 1.f / lsum;
  for (int s = t; s < SS; s += 256){
    float p = sc_s[s] * invl;
    sc_s[s] = p;
    prob_ws[(size_t)rg * SS + s] = p;
  }
  __syncthreads();

  // context = prob @ enc  (4 independent accumulators to break dep chain)
  for (int k = t; k < HH; k += 256){
    float c0 = 0.f, c1 = 0.f, c2 = 0.f, c3 = 0.f;
    const float* ek = encb + k;
    int s = 0;
    for (; s + 3 < len; s += 4){
      c0 += sc_s[s]     * ek[(size_t)s * HH];
      c1 += sc_s[s + 1] * ek[(size_t)(s + 1) * HH];
      c2 += sc_s[s + 2] * ek[(size_t)(s + 2) * HH];
      c3 += sc_s[s + 3] * ek[(size_t)(s + 3) * HH];
    }
    for (; s < len; ++s) c0 += sc_s[s] * ek[(size_t)s * HH];
    ctx_s[k] = (c0 + c1) + (c2 + c3);
  }
  __syncthreads();

  float sa = 0.f;
  for (int k = t; k < HH; k += 256){
    sa += Wr_w[k]          * hn_s[k]
        + Wr_w[HH + k]     * ctx_s[k]
        + Wr_w[2 * HH + k] * x_ws[(size_t)rg * HH + k];
  }
  sa = wred_sum(sa);
  if ((t & 63) == 0) red[t >> 6] = sa;
  __syncthreads();
  sa = red[0] + red[1] + red[2] + red[3];
  if (t == 0) sw_ws[rg] = sigm(sa + Wr_b[0]);

  if (wi == 0){
    float ga[GG] = {0.f, 0.f, 0.f};
    for (int k = t; k < HH; k += 256){
      float cv = ctx_s[k];
      ga[0] += Wg_w[k] * cv;
      ga[1] += Wg_w[HH + k] * cv;
      ga[2] += Wg_w[2 * HH + k] * cv;
    }
    #pragma unroll
    for (int g = 0; g < GG; ++g){
      ga[g] = wred_sum(ga[g]);
      if ((t & 63) == 0) redg[g][t >> 6] = ga[g];
    }
    __syncthreads();
    if (t < GG)
      d_out[(size_t)NSLOT * BB * TT * VV + (size_t)rg * GG + t] =
          redg[t][0] + redg[t][1] + redg[t][2] + redg[t][3] + Wg_b[t];
  }

  // x <- emb[target] (next step's input): f32 row + hi/lo A-frags
  const int tgt = target[batch * (NSLOT * TT) + slot * TT + wi];
  const float* embrow = emb + (size_t)tgt * HH;
  for (int k = t; k < HH; k += 256)
    x_ws[(size_t)rg * HH + k] = embrow[k];
  if (t < KP / 8){
    const int kk = t >> 2, lg = t & 3;
    bf16x8 oh, ol;
    #pragma unroll
    for (int j = 0; j < 8; ++j){
      int k = t * 8 + j;
      if (k < HH){
        float v = embrow[k];
        short hb = f2bfs(v);
        oh[j] = hb; ol[j] = f2bfs(v - bfu((u16)hb));
      } else { oh[j] = 0; ol[j] = 0; }
    }
    size_t off = ((size_t)rtile * NKK + kk) * FRAG_STRIDE + (lg * 16 + rl) * 8;
    *reinterpret_cast<bf16x8*>(x_hi + off) = oh;
    *reinterpret_cast<bf16x8*>(x_lo + off) = ol;
  }
}

// ---- combine partials + pointer mix; expand bf16 logits to f32 IN PLACE.
// bf16 row staged in REGISTERS (not LDS) -> 80 KB LDS -> 2 blocks/CU.
__global__ __launch_bounds__(256) void k_finalize(
    float* __restrict__ logits_out, const float* __restrict__ prob_ws,
    const float* __restrict__ pmax_ws, const float* __restrict__ psum_ws,
    const float* __restrict__ sw_ws, const int* __restrict__ story,
    const int* __restrict__ lens, int wi)
{
  __shared__ float pctx[VV];          // 80 KB
  __shared__ float red[4];
  const int t = threadIdx.x;
  const int r = blockIdx.x;
  const int batch = r % BB;
  for (int v = t; v < VV; v += 256) pctx[v] = 0.f;
  __syncthreads();
  const int len = lens[batch];
  for (int s = t; s < SS; s += 256){
    if (s < len)
      atomicAdd(&pctx[story[batch * SS + s]], prob_ws[(size_t)r * SS + s]);
  }

  // stage this thread's slice of the bf16 logit row into registers.
  // (VV/8=2500 uint4 chunks; <=10 per thread)
  float* lrow = logits_out + ((size_t)r * TT + wi) * VV;
  const uint4* l16 = reinterpret_cast<const uint4*>(lrow);
  uint4 stage[10];
  {
    int ns = 0;
    for (int i = t; i < VV / 8; i += 256) stage[ns++] = l16[i];
  }

  // combine 157*2 softmax partials
  const float* pm = pmax_ws + (size_t)r * (NBN * 2);
  const float* ps = psum_ws + (size_t)r * (NBN * 2);
  float m = -3.0e38f;
  for (int i = t; i < NBN * 2; i += 256) m = fmaxf(m, pm[i]);
  m = wred_max(m);
  if ((t & 63) == 0) red[t >> 6] = m;
  __syncthreads();                     // drains staging loads + pctx atomics
  m = fmaxf(fmaxf(red[0], red[1]), fmaxf(red[2], red[3]));
  float lsum = 0.f;
  for (int i = t; i < NBN * 2; i += 256) lsum += ps[i] * __expf(pm[i] - m);
  lsum = wred_sum(lsum);
  __syncthreads();
  if ((t & 63) == 0) red[t >> 6] = lsum;
  __syncthreads();
  lsum = red[0] + red[1] + red[2] + red[3];

  const float sw = sw_ws[r];
  const float invl = sw / lsum;
  const float osw = 1.f - sw;
  {
    int ns = 0;
    for (int i = t; i < VV / 8; i += 256){
      uint4 q = stage[ns++];
      int v = i * 8;
      float4 o0, o1;
      o0.x = __expf(bfu_lo(q.x) - m) * invl + osw * pctx[v + 0];
      o0.y = __expf(bfu_hi(q.x) - m) * invl + osw * pctx[v + 1];
      o0.z = __expf(bfu_lo(q.y) - m) * invl + osw * pctx[v + 2];
      o0.w = __expf(bfu_hi(q.y) - m) * invl + osw * pctx[v + 3];
      o1.x = __expf(bfu_lo(q.z) - m) * invl + osw * pctx[v + 4];
      o1.y = __expf(bfu_hi(q.z) - m) * invl + osw * pctx[v + 5];
      o1.z = __expf(bfu_lo(q.w) - m) * invl + osw * pctx[v + 6];
      o1.w = __expf(bfu_hi(q.w) - m) * invl + osw * pctx[v + 7];
      *reinterpret_cast<float4*>(lrow + v)     = o0;
      *reinterpret_cast<float4*>(lrow + v + 4) = o1;
    }
  }
}

extern "C" void kernel_launch(void* const* d_in, const int* in_sizes, int n_in,
                              void* d_out, int out_size, void* d_ws, size_t ws_size,
                              hipStream_t stream)
{
  (void)in_sizes; (void)n_in; (void)out_size; (void)ws_size;
  const float* eh    = (const float*)d_in[0];
  const float* enc   = (const float*)d_in[1];
  const float* semb  = (const float*)d_in[2];
  const float* emb   = (const float*)d_in[3];
  const float* W_ih  = (const float*)d_in[4];
  const float* W_hh  = (const float*)d_in[5];
  const float* b_ih  = (const float*)d_in[6];
  const float* b_hh  = (const float*)d_in[7];
  const float* Wr_w  = (const float*)d_in[8];
  const float* Wr_b  = (const float*)d_in[9];
  const float* Wg_w  = (const float*)d_in[10];
  const float* Wg_b  = (const float*)d_in[11];
  const int* story = (const int*)d_in[12];
  const int* tgt   = (const int*)d_in[13];
  const int* lens  = (const int*)d_in[14];
  float* out = (float*)d_out;

  // ws layout (f32 offsets); total ~30.4 MB
  float* ws      = (float*)d_ws;
  float* h_ws    = ws;                        // 192000
  float* x_ws    = ws + 192000;               // 192000
  float* prob_ws = ws + 384000;               // 192000
  float* sw_ws   = ws + 576000;               // 512
  float* gi_ws   = ws + 576512;               // 576000
  float* gh_ws   = ws + 1152512;              // 576000
  float* pmax_ws = ws + 1728512;              // 151040
  float* psum_ws = ws + 1879552;              // 151040
  short* h_hi    = (short*)(ws + 2030592);    // 30*13*512 shorts (99840 f32)
  short* emb_bf  = (short*)(ws + 2130432);    // 1256*13*512 shorts (4179968 f32)
  short* Wih_hi  = (short*)(ws + 6310400);    // 75*13*512 shorts (249600 f32)
  short* Wih_lo  = (short*)(ws + 6560000);
  short* Whh_hi  = (short*)(ws + 6809600);
  short* Whh_lo  = (short*)(ws + 7059200);
  short* x_hi    = (short*)(ws + 7308800);    // 99840 f32 each
  short* x_lo    = (short*)(ws + 7408640);
  short* h_lo    = (short*)(ws + 7508480);    // ends 7608320

  k_cast_emb<<<2048, 256, 0, stream>>>(emb, emb_bf);
  k_cast_W<<<512, 256, 0, stream>>>(W_ih, W_hh, Wih_hi, Wih_lo, Whh_hi, Whh_lo);
  k_init<<<750, 256, 0, stream>>>(eh, semb, h_ws, x_ws);
  k_split_xh<<<195, 256, 0, stream>>>(h_ws, x_ws, h_hi, h_lo, x_hi, x_lo);
  for (int wi = 0; wi < TT; ++wi){
    dim3 gg(4, 10, 2);
    k_gemm2_mfma<<<gg, 256, 0, stream>>>(x_hi, x_lo, h_hi, h_lo,
                                         Wih_hi, Wih_lo, Whh_hi, Whh_lo,
                                         gi_ws, gh_ws);
    k_att<<<BSR, 256, 0, stream>>>(enc, emb, b_ih, b_hh, Wr_w, Wr_b, Wg_w, Wg_b,
                                   tgt, lens, gi_ws, gh_ws, h_ws, x_ws,
                                   h_hi, h_lo, x_hi, x_lo,
                                   prob_ws, sw_ws, out, wi);
    dim3 gl(4, NBN);
    k_logits_mfma<<<gl, 256, 0, stream>>>(h_hi, emb_bf, out, pmax_ws, psum_ws, wi);
    k_finalize<<<BSR, 256, 0, stream>>>(out, prob_ws, pmax_ws, psum_ws,
                                        sw_ws, story, lens, wi);
  }
}

// Round 13
// 973.114 us; speedup vs baseline: 1.1736x; 1.0253x over previous
//
#include <hip/hip_runtime.h>
#include <hip/hip_bf16.h>

#define NSLOT 30
#define BB    16
#define TT    8
#define SS    400
#define HH    400
#define KP    416           // K padded to 13*32 for MFMA
#define NKK   13            // KP/32
#define VV    20000
#define GG    3
#define BSR   480           // NSLOT*BB fused decode rows
#define NBN   157           // ceil(VV/128) col-blocks
#define NCT   1256          // NBN*8 col tiles in emb frag buffer (zero-padded)
#define NG2   1200          // gemm2 output cols (3*HH)
#define NCT2  75            // NG2/16 col tiles for W frags
#define NRT   30            // BSR/16 row tiles
#define FRAG_STRIDE 512     // shorts per (tile,kk): 64 lanes * 8

typedef unsigned short u16;
typedef __attribute__((ext_vector_type(8))) short bf16x8;
typedef __attribute__((ext_vector_type(4))) float f32x4;

__device__ __forceinline__ short f2bfs(float f){
  __hip_bfloat16 h = __float2bfloat16(f);
  union { __hip_bfloat16 b; short u; } v; v.b = h; return v.u;
}
__device__ __forceinline__ unsigned int pack2(float lo, float hi){
  return (unsigned int)(u16)f2bfs(lo) | ((unsigned int)(u16)f2bfs(hi) << 16);
}
__device__ __forceinline__ float bfu(u16 u){
  union { unsigned int i; float f; } v; v.i = ((unsigned int)u) << 16; return v.f;
}
__device__ __forceinline__ float bfu_lo(unsigned int u){
  union { unsigned int i; float f; } v; v.i = u << 16; return v.f;
}
__device__ __forceinline__ float bfu_hi(unsigned int u){
  union { unsigned int i; float f; } v; v.i = u & 0xffff0000u; return v.f;
}
__device__ __forceinline__ float sigm(float x){ return 1.f / (1.f + __expf(-x)); }
__device__ __forceinline__ float tanh_fast(float x){
  float e = __expf(2.f * x);
  return 1.f - 2.f / (e + 1.f);
}
__device__ __forceinline__ float wred_max(float v){
  #pragma unroll
  for (int off = 32; off; off >>= 1) v = fmaxf(v, __shfl_xor(v, off, 64));
  return v;
}
__device__ __forceinline__ float wred_sum(float v){
  #pragma unroll
  for (int off = 32; off; off >>= 1) v += __shfl_xor(v, off, 64);
  return v;
}

// ---- init: h0/x0 f32 arrays + hi/lo A-frags, fused one pass.
// Unit u decomposes as k_split_xh; note r = rtile*16+rl => slot=rtile, batch=rl.
__global__ __launch_bounds__(256) void k_init_all(
    const float* __restrict__ eh, const float* __restrict__ semb,
    float* __restrict__ h_ws, float* __restrict__ x_ws,
    short* __restrict__ h_hi, short* __restrict__ h_lo,
    short* __restrict__ x_hi, short* __restrict__ x_lo)
{
  const int NU = NRT * NKK * 64;
  for (int u = blockIdx.x * 256 + threadIdx.x; u < 2 * NU; u += gridDim.x * 256){
    int uu = u; int sel = 0;
    if (uu >= NU){ uu -= NU; sel = 1; }      // sel 0: h (from eh), 1: x (semb)
    short* ph = sel ? x_hi : h_hi;
    short* pl = sel ? x_lo : h_lo;
    float* fw = sel ? x_ws : h_ws;
    int lane = uu & 63, kt = uu >> 6;
    int rtile = kt / NKK, kk = kt - rtile * NKK;
    int lg = lane >> 4, rl = lane & 15;
    int r = rtile * 16 + rl, k = kk * 32 + lg * 8;
    const float* src = sel ? (semb + (size_t)rtile * HH)   // slot = rtile
                           : (eh   + (size_t)rl * HH);     // batch = rl
    bf16x8 oh, ol;
    #pragma unroll
    for (int j = 0; j < 8; ++j){
      if (k + j < HH){
        float v = src[k + j];
        short hb = f2bfs(v);
        oh[j] = hb; ol[j] = f2bfs(v - bfu((u16)hb));
        fw[(size_t)r * HH + k + j] = v;
      } else { oh[j] = 0; ol[j] = 0; }
    }
    *reinterpret_cast<bf16x8*>(ph + (size_t)uu * 8) = oh;
    *reinterpret_cast<bf16x8*>(pl + (size_t)uu * 8) = ol;
  }
}

// ---- one-time: split W_ih, W_hh into hi/lo B-frags [75 ctile][13 kk][512]
__global__ __launch_bounds__(256) void k_cast_W(
    const float* __restrict__ Wih, const float* __restrict__ Whh,
    short* __restrict__ Wih_hi, short* __restrict__ Wih_lo,
    short* __restrict__ Whh_hi, short* __restrict__ Whh_lo)
{
  const int NU = NCT2 * NKK * 64;
  for (int u = blockIdx.x * 256 + threadIdx.x; u < 2 * NU; u += gridDim.x * 256){
    int uu = u; int sel = 0;
    if (uu >= NU){ uu -= NU; sel = 1; }
    const float* W = sel ? Whh : Wih;
    short* ph = sel ? Whh_hi : Wih_hi;
    short* pl = sel ? Whh_lo : Wih_lo;
    int lane = uu & 63, kt = uu >> 6;
    int ctile = kt / NKK, kk = kt - ctile * NKK;
    int lg = lane >> 4, cl = lane & 15;
    int c = ctile * 16 + cl, k = kk * 32 + lg * 8;
    bf16x8 oh, ol;
    #pragma unroll
    for (int j = 0; j < 8; ++j){
      if (k + j < HH){
        float v = W[(size_t)c * HH + k + j];
        short hb = f2bfs(v);
        oh[j] = hb; ol[j] = f2bfs(v - bfu((u16)hb));
      } else { oh[j] = 0; ol[j] = 0; }
    }
    *reinterpret_cast<bf16x8*>(ph + (size_t)uu * 8) = oh;
    *reinterpret_cast<bf16x8*>(pl + (size_t)uu * 8) = ol;
  }
}

// ---- one-time: emb f32[20000][400] -> bf16 MFMA-fragment layout
__global__ __launch_bounds__(256) void k_cast_emb(const float* __restrict__ emb,
                                                  short* __restrict__ ebf)
{
  const int nunit = NCT * NKK * 64;
  for (int u = blockIdx.x * 256 + threadIdx.x; u < nunit; u += gridDim.x * 256){
    int lane = u & 63;
    int kt = u >> 6;
    int ctile = kt / NKK, kk = kt - ctile * NKK;
    int lg = lane >> 4, cl = lane & 15;
    int c = ctile * 16 + cl;
    int k = kk * 32 + lg * 8;
    bf16x8 o;
    if (c < VV && k < HH){
      const float* src = emb + (size_t)c * HH + k;
      #pragma unroll
      for (int j = 0; j < 8; ++j) o[j] = f2bfs(src[j]);
    } else {
      #pragma unroll
      for (int j = 0; j < 8; ++j) o[j] = 0;
    }
    *reinterpret_cast<bf16x8*>(ebf + (size_t)u * 8) = o;
  }
}

// ---- gemm2 body: gi = x*W_ih^T (z=0) / gh = h*W_hh^T (z=1), split-bf16 MFMA.
__device__ __forceinline__ void gemm2_body(
    int bM, int bN, int z, int t,
    const short* __restrict__ x_hi, const short* __restrict__ x_lo,
    const short* __restrict__ h_hi, const short* __restrict__ h_lo,
    const short* __restrict__ Wih_hi, const short* __restrict__ Wih_lo,
    const short* __restrict__ Whh_hi, const short* __restrict__ Whh_lo,
    float* __restrict__ gi, float* __restrict__ gh)
{
  const int lane = t & 63, wid = t >> 6;
  const int wr = wid >> 1, wc = wid & 1;
  const int l15 = lane & 15, lg = lane >> 4;

  const short* A_hi = z ? h_hi : x_hi;
  const short* A_lo = z ? h_lo : x_lo;
  const short* B_hi = z ? Whh_hi : Wih_hi;
  const short* B_lo = z ? Whh_lo : Wih_lo;
  float* C = z ? gh : gi;

  const short *ah[4], *al[4], *bh[4], *bl[4];
  #pragma unroll
  for (int m = 0; m < 4; ++m){
    int rtile = min(bM * 8 + wr * 4 + m, NRT - 1);
    size_t off = (size_t)rtile * (NKK * FRAG_STRIDE) + lane * 8;
    ah[m] = A_hi + off; al[m] = A_lo + off;
  }
  #pragma unroll
  for (int n = 0; n < 4; ++n){
    int ctile = min(bN * 8 + wc * 4 + n, NCT2 - 1);
    size_t off = (size_t)ctile * (NKK * FRAG_STRIDE) + lane * 8;
    bh[n] = B_hi + off; bl[n] = B_lo + off;
  }

  f32x4 acc[4][4];
  #pragma unroll
  for (int m = 0; m < 4; ++m)
    #pragma unroll
    for (int n = 0; n < 4; ++n)
      acc[m][n] = (f32x4){0.f, 0.f, 0.f, 0.f};

  #pragma unroll
  for (int kk = 0; kk < NKK; ++kk){
    const int ko = kk * FRAG_STRIDE;
    bf16x8 ah_r[4], al_r[4];
    #pragma unroll
    for (int m = 0; m < 4; ++m){
      ah_r[m] = *reinterpret_cast<const bf16x8*>(ah[m] + ko);
      al_r[m] = *reinterpret_cast<const bf16x8*>(al[m] + ko);
    }
    #pragma unroll
    for (int n = 0; n < 4; ++n){
      bf16x8 bhv = *reinterpret_cast<const bf16x8*>(bh[n] + ko);
      bf16x8 blv = *reinterpret_cast<const bf16x8*>(bl[n] + ko);
      #pragma unroll
      for (int m = 0; m < 4; ++m){
        acc[m][n] = __builtin_amdgcn_mfma_f32_16x16x32_bf16(ah_r[m], bhv, acc[m][n], 0, 0, 0);
        acc[m][n] = __builtin_amdgcn_mfma_f32_16x16x32_bf16(ah_r[m], blv, acc[m][n], 0, 0, 0);
        acc[m][n] = __builtin_amdgcn_mfma_f32_16x16x32_bf16(al_r[m], bhv, acc[m][n], 0, 0, 0);
      }
    }
  }

  #pragma unroll
  for (int m = 0; m < 4; ++m){
    #pragma unroll
    for (int q = 0; q < 4; ++q){
      int row = bM * 128 + wr * 64 + m * 16 + lg * 4 + q;
      if (row < BSR){
        #pragma unroll
        for (int n = 0; n < 4; ++n){
          int col = bN * 128 + wc * 64 + n * 16 + l15;
          if (col < NG2) C[(size_t)row * NG2 + col] = acc[m][n][q];
        }
      }
    }
  }
}

__global__ __launch_bounds__(256) void k_gemm2_mfma(
    const short* __restrict__ x_hi, const short* __restrict__ x_lo,
    const short* __restrict__ h_hi, const short* __restrict__ h_lo,
    const short* __restrict__ Wih_hi, const short* __restrict__ Wih_lo,
    const short* __restrict__ Whh_hi, const short* __restrict__ Whh_lo,
    float* __restrict__ gi, float* __restrict__ gh)
{
  gemm2_body(blockIdx.x, blockIdx.y, blockIdx.z, threadIdx.x,
             x_hi, x_lo, h_hi, h_lo, Wih_hi, Wih_lo, Whh_hi, Whh_lo, gi, gh);
}

// --------- logits = h x emb^T via MFMA bf16, 128x128 block tile.
__global__ __launch_bounds__(256) void k_logits_mfma(
    const short* __restrict__ hbf, const short* __restrict__ ebf,
    float* __restrict__ out, float* __restrict__ pmax_ws,
    float* __restrict__ psum_ws, int wi)
{
  const int t = threadIdx.x;
  const int lane = t & 63, wid = t >> 6;
  const int wr = wid >> 1, wc = wid & 1;
  const int l15 = lane & 15, lg = lane >> 4;
  const int bM = blockIdx.x, bN = blockIdx.y;

  const short* ap[4];
  const short* bp[4];
  #pragma unroll
  for (int m = 0; m < 4; ++m){
    int rtile = bM * 8 + wr * 4 + m;
    ap[m] = hbf + (size_t)min(rtile, NRT - 1) * (NKK * FRAG_STRIDE) + lane * 8;
  }
  #pragma unroll
  for (int n = 0; n < 4; ++n){
    int ctile = bN * 8 + wc * 4 + n;
    bp[n] = ebf + (size_t)ctile * (NKK * FRAG_STRIDE) + lane * 8;
  }

  f32x4 acc[4][4];
  #pragma unroll
  for (int m = 0; m < 4; ++m)
    #pragma unroll
    for (int n = 0; n < 4; ++n)
      acc[m][n] = (f32x4){0.f, 0.f, 0.f, 0.f};

  #pragma unroll
  for (int kk = 0; kk < NKK; ++kk){
    const int ko = kk * FRAG_STRIDE;
    bf16x8 a[4];
    #pragma unroll
    for (int m = 0; m < 4; ++m)
      a[m] = *reinterpret_cast<const bf16x8*>(ap[m] + ko);
    #pragma unroll
    for (int n = 0; n < 4; ++n){
      bf16x8 b = *reinterpret_cast<const bf16x8*>(bp[n] + ko);
      #pragma unroll
      for (int m = 0; m < 4; ++m)
        acc[m][n] = __builtin_amdgcn_mfma_f32_16x16x32_bf16(a[m], b, acc[m][n], 0, 0, 0);
    }
  }

  #pragma unroll
  for (int m = 0; m < 4; ++m){
    #pragma unroll
    for (int q = 0; q < 4; ++q){
      int row = bM * 128 + wr * 64 + m * 16 + lg * 4 + q;
      u16* lrow16 = reinterpret_cast<u16*>(out + ((size_t)row * TT + wi) * VV);
      #pragma unroll
      for (int n = 0; n < 4; ++n){
        float v = acc[m][n][q];
        float vp = __shfl_xor(v, 1, 64);
        int col = bN * 128 + wc * 64 + n * 16 + l15;
        if (((l15 & 1) == 0) && row < BSR && col < VV)
          *reinterpret_cast<unsigned int*>(lrow16 + col) = pack2(v, vp);
      }
    }
    f32x4 rmax, rsum;
    #pragma unroll
    for (int q = 0; q < 4; ++q){
      float mx = -3.0e38f;
      #pragma unroll
      for (int n = 0; n < 4; ++n){
        int col = bN * 128 + wc * 64 + n * 16 + l15;
        float v = (col < VV) ? acc[m][n][q] : -3.0e38f;
        mx = fmaxf(mx, v);
      }
      #pragma unroll
      for (int off = 1; off < 16; off <<= 1) mx = fmaxf(mx, __shfl_xor(mx, off, 64));
      float sm = 0.f;
      #pragma unroll
      for (int n = 0; n < 4; ++n){
        int col = bN * 128 + wc * 64 + n * 16 + l15;
        if (col < VV) sm += __expf(acc[m][n][q] - mx);
      }
      #pragma unroll
      for (int off = 1; off < 16; off <<= 1) sm += __shfl_xor(sm, off, 64);
      rmax[q] = mx; rsum[q] = sm;
    }
    if (l15 == 0){
      #pragma unroll
      for (int q = 0; q < 4; ++q){
        int row = bM * 128 + wr * 64 + m * 16 + lg * 4 + q;
        if (row < BSR){
          size_t pidx = ((size_t)row * NBN + bN) * 2 + wc;
          pmax_ws[pidx] = rmax[q];
          psum_ws[pidx] = rsum[q];
        }
      }
    }
  }
}

// ----------- per-row: GRU gates -> h_new (+hi/lo frag), attention, softmax,
//             context, switch, gate (wi==0), teacher-forcing x (+hi/lo frag).
__global__ __launch_bounds__(256) void k_att(
    const float* __restrict__ enc, const float* __restrict__ emb,
    const float* __restrict__ b_ih, const float* __restrict__ b_hh,
    const float* __restrict__ Wr_w, const float* __restrict__ Wr_b,
    const float* __restrict__ Wg_w, const float* __restrict__ Wg_b,
    const int* __restrict__ target, const int* __restrict__ lens,
    const float* __restrict__ gi_ws, const float* __restrict__ gh_ws,
    float* __restrict__ h_ws, float* __restrict__ x_ws,
    short* __restrict__ h_hi, short* __restrict__ h_lo,
    short* __restrict__ x_hi, short* __restrict__ x_lo,
    float* __restrict__ prob_ws, float* __restrict__ sw_ws,
    float* __restrict__ d_out, int wi)
{
  __shared__ float hn_s[HH];
  __shared__ float sc_s[SS];
  __shared__ float ctx_s[HH];
  __shared__ float red[4];
  __shared__ float redg[GG][4];

  const int t = threadIdx.x;
  const int rg = blockIdx.x;
  const int batch = rg % BB, slot = rg / BB;
  const int len = lens[batch];
  const int rtile = rg >> 4, rl = rg & 15;

  // GRU gates -> h_new
  const float* gir = gi_ws + (size_t)rg * NG2;
  const float* ghr = gh_ws + (size_t)rg * NG2;
  for (int k = t; k < HH; k += 256){
    float irv = gir[k]          + b_ih[k];
    float izv = gir[HH + k]     + b_ih[HH + k];
    float inv = gir[2 * HH + k] + b_ih[2 * HH + k];
    float hrv = ghr[k]          + b_hh[k];
    float hzv = ghr[HH + k]     + b_hh[HH + k];
    float hnv = ghr[2 * HH + k] + b_hh[2 * HH + k];
    float rr = sigm(irv + hrv);
    float zz = sigm(izv + hzv);
    float nn = tanh_fast(inv + rr * hnv);
    float hold = h_ws[(size_t)rg * HH + k];
    float hnew = (1.f - zz) * nn + zz * hold;
    hn_s[k] = hnew;
    h_ws[(size_t)rg * HH + k] = hnew;
  }
  __syncthreads();

  // h_new -> hi/lo A-frags
  if (t < KP / 8){                      // 52 units
    const int kk = t >> 2, lg = t & 3;
    bf16x8 oh, ol;
    #pragma unroll
    for (int j = 0; j < 8; ++j){
      int k = t * 8 + j;
      if (k < HH){
        float v = hn_s[k];
        short hb = f2bfs(v);
        oh[j] = hb; ol[j] = f2bfs(v - bfu((u16)hb));
      } else { oh[j] = 0; ol[j] = 0; }
    }
    size_t off = ((size_t)rtile * NKK + kk) * FRAG_STRIDE + (lg * 16 + rl) * 8;
    *reinterpret_cast<bf16x8*>(h_hi + off) = oh;
    *reinterpret_cast<bf16x8*>(h_lo + off) = ol;
  }

  const float* encb = enc + (size_t)batch * SS * HH;
  float lmax = -3.0e38f;
  for (int s = t; s < SS; s += 256){
    if (s < len){
      const float4* er4 = reinterpret_cast<const float4*>(encb + (size_t)s * HH);
      float dot = 0.f;
      for (int k4 = 0; k4 < HH / 4; ++k4){
        float4 e = er4[k4];
        float4 hv = *reinterpret_cast<const float4*>(&hn_s[k4 * 4]);
        dot += e.x*hv.x + e.y*hv.y + e.z*hv.z + e.w*hv.w;
      }
      sc_s[s] = dot;
      lmax = fmaxf(lmax, dot);
    }
  }
  lmax = wred_max(lmax);
  if ((t & 63) == 0) red[t >> 6] = lmax;
  __syncthreads();
  lmax = fmaxf(fmaxf(red[0], red[1]), fmaxf(red[2], red[3]));
  float lsum = 0.f;
  for (int s = t; s < SS; s += 256){
    float e = (s < len) ? __expf(sc_s[s] - lmax) : 0.f;
    sc_s[s] = e;
    lsum += e;
  }
  lsum = wred_sum(lsum);
  __syncthreads();
  if ((t & 63) == 0) red[t >> 6] = lsum;
  __syncthreads();
  lsum = red[0] + red[1] + red[2] + red[3];
  float invl = 1.f / lsum;
  for (int s = t; s < SS; s += 256){
    float p = sc_s[s] * invl;
    sc_s[s] = p;
    prob_ws[(size_t)rg * SS + s] = p;
  }
  __syncthreads();

  // context = prob @ enc  (4 independent accumulators to break dep chain)
  for (int k = t; k < HH; k += 256){
    float c0 = 0.f, c1 = 0.f, c2 = 0.f, c3 = 0.f;
    const float* ek = encb + k;
    int s = 0;
    for (; s + 3 < len; s += 4){
      c0 += sc_s[s]     * ek[(size_t)s * HH];
      c1 += sc_s[s + 1] * ek[(size_t)(s + 1) * HH];
      c2 += sc_s[s + 2] * ek[(size_t)(s + 2) * HH];
      c3 += sc_s[s + 3] * ek[(size_t)(s + 3) * HH];
    }
    for (; s < len; ++s) c0 += sc_s[s] * ek[(size_t)s * HH];
    ctx_s[k] = (c0 + c1) + (c2 + c3);
  }
  __syncthreads();

  float sa = 0.f;
  for (int k = t; k < HH; k += 256){
    sa += Wr_w[k]          * hn_s[k]
        + Wr_w[HH + k]     * ctx_s[k]
        + Wr_w[2 * HH + k] * x_ws[(size_t)rg * HH + k];
  }
  sa = wred_sum(sa);
  if ((t & 63) == 0) red[t >> 6] = sa;
  __syncthreads();
  sa = red[0] + red[1] + red[2] + red[3];
  if (t == 0) sw_ws[rg] = sigm(sa + Wr_b[0]);

  if (wi == 0){
    float ga[GG] = {0.f, 0.f, 0.f};
    for (int k = t; k < HH; k += 256){
      float cv = ctx_s[k];
      ga[0] += Wg_w[k] * cv;
      ga[1] += Wg_w[HH + k] * cv;
      ga[2] += Wg_w[2 * HH + k] * cv;
    }
    #pragma unroll
    for (int g = 0; g < GG; ++g){
      ga[g] = wred_sum(ga[g]);
      if ((t & 63) == 0) redg[g][t >> 6] = ga[g];
    }
    __syncthreads();
    if (t < GG)
      d_out[(size_t)NSLOT * BB * TT * VV + (size_t)rg * GG + t] =
          redg[t][0] + redg[t][1] + redg[t][2] + redg[t][3] + Wg_b[t];
  }

  // x <- emb[target] (next step's input): f32 row + hi/lo A-frags
  const int tgt = target[batch * (NSLOT * TT) + slot * TT + wi];
  const float* embrow = emb + (size_t)tgt * HH;
  for (int k = t; k < HH; k += 256)
    x_ws[(size_t)rg * HH + k] = embrow[k];
  if (t < KP / 8){
    const int kk = t >> 2, lg = t & 3;
    bf16x8 oh, ol;
    #pragma unroll
    for (int j = 0; j < 8; ++j){
      int k = t * 8 + j;
      if (k < HH){
        float v = embrow[k];
        short hb = f2bfs(v);
        oh[j] = hb; ol[j] = f2bfs(v - bfu((u16)hb));
      } else { oh[j] = 0; ol[j] = 0; }
    }
    size_t off = ((size_t)rtile * NKK + kk) * FRAG_STRIDE + (lg * 16 + rl) * 8;
    *reinterpret_cast<bf16x8*>(x_hi + off) = oh;
    *reinterpret_cast<bf16x8*>(x_lo + off) = ol;
  }
}

// ---- FUSED: blocks [0,480) = finalize(wi); blocks [480,560) = gemm2(wi+1).
// finalize: combine partials + pointer mix; bf16 row staged in registers;
// 80 KB pctx LDS -> 2 blocks/CU. gemm2 half skipped when do_gemm==0 (wi==7).
__global__ __launch_bounds__(256) void k_fin_gemm2(
    float* __restrict__ logits_out, const float* __restrict__ prob_ws,
    const float* __restrict__ pmax_ws, const float* __restrict__ psum_ws,
    const float* __restrict__ sw_ws, const int* __restrict__ story,
    const int* __restrict__ lens, int wi,
    const short* __restrict__ x_hi, const short* __restrict__ x_lo,
    const short* __restrict__ h_hi, const short* __restrict__ h_lo,
    const short* __restrict__ Wih_hi, const short* __restrict__ Wih_lo,
    const short* __restrict__ Whh_hi, const short* __restrict__ Whh_lo,
    float* __restrict__ gi, float* __restrict__ gh, int do_gemm)
{
  __shared__ float pctx[VV];          // 80 KB (unused by gemm2 blocks)
  __shared__ float red[4];
  const int t = threadIdx.x;

  if (blockIdx.x >= BSR){
    if (!do_gemm) return;
    int b = blockIdx.x - BSR;                 // [0,80)
    int bM = b & 3, bN = (b >> 2) % 10, z = b / 40;
    gemm2_body(bM, bN, z, t, x_hi, x_lo, h_hi, h_lo,
               Wih_hi, Wih_lo, Whh_hi, Whh_lo, gi, gh);
    return;
  }

  const int r = blockIdx.x;
  const int batch = r % BB;
  for (int v = t; v < VV; v += 256) pctx[v] = 0.f;
  __syncthreads();
  const int len = lens[batch];
  for (int s = t; s < SS; s += 256){
    if (s < len)
      atomicAdd(&pctx[story[batch * SS + s]], prob_ws[(size_t)r * SS + s]);
  }

  // stage this thread's slice of the bf16 logit row into registers.
  float* lrow = logits_out + ((size_t)r * TT + wi) * VV;
  const uint4* l16 = reinterpret_cast<const uint4*>(lrow);
  uint4 stage[10];
  {
    int ns = 0;
    for (int i = t; i < VV / 8; i += 256) stage[ns++] = l16[i];
  }

  // combine 157*2 softmax partials
  const float* pm = pmax_ws + (size_t)r * (NBN * 2);
  const float* ps = psum_ws + (size_t)r * (NBN * 2);
  float m = -3.0e38f;
  for (int i = t; i < NBN * 2; i += 256) m = fmaxf(m, pm[i]);
  m = wred_max(m);
  if ((t & 63) == 0) red[t >> 6] = m;
  __syncthreads();                     // drains staging loads + pctx atomics
  m = fmaxf(fmaxf(red[0], red[1]), fmaxf(red[2], red[3]));
  float lsum = 0.f;
  for (int i = t; i < NBN * 2; i += 256) lsum += ps[i] * __expf(pm[i] - m);
  lsum = wred_sum(lsum);
  __syncthreads();
  if ((t & 63) == 0) red[t >> 6] = lsum;
  __syncthreads();
  lsum = red[0] + red[1] + red[2] + red[3];

  const float sw = sw_ws[r];
  const float invl = sw / lsum;
  const float osw = 1.f - sw;
  {
    int ns = 0;
    for (int i = t; i < VV / 8; i += 256){
      uint4 q = stage[ns++];
      int v = i * 8;
      float4 o0, o1;
      o0.x = __expf(bfu_lo(q.x) - m) * invl + osw * pctx[v + 0];
      o0.y = __expf(bfu_hi(q.x) - m) * invl + osw * pctx[v + 1];
      o0.z = __expf(bfu_lo(q.y) - m) * invl + osw * pctx[v + 2];
      o0.w = __expf(bfu_hi(q.y) - m) * invl + osw * pctx[v + 3];
      o1.x = __expf(bfu_lo(q.z) - m) * invl + osw * pctx[v + 4];
      o1.y = __expf(bfu_hi(q.z) - m) * invl + osw * pctx[v + 5];
      o1.z = __expf(bfu_lo(q.w) - m) * invl + osw * pctx[v + 6];
      o1.w = __expf(bfu_hi(q.w) - m) * invl + osw * pctx[v + 7];
      *reinterpret_cast<float4*>(lrow + v)     = o0;
      *reinterpret_cast<float4*>(lrow + v + 4) = o1;
    }
  }
}

extern "C" void kernel_launch(void* const* d_in, const int* in_sizes, int n_in,
                              void* d_out, int out_size, void* d_ws, size_t ws_size,
                              hipStream_t stream)
{
  (void)in_sizes; (void)n_in; (void)out_size; (void)ws_size;
  const float* eh    = (const float*)d_in[0];
  const float* enc   = (const float*)d_in[1];
  const float* semb  = (const float*)d_in[2];
  const float* emb   = (const float*)d_in[3];
  const float* W_ih  = (const float*)d_in[4];
  const float* W_hh  = (const float*)d_in[5];
  const float* b_ih  = (const float*)d_in[6];
  const float* b_hh  = (const float*)d_in[7];
  const float* Wr_w  = (const float*)d_in[8];
  const float* Wr_b  = (const float*)d_in[9];
  const float* Wg_w  = (const float*)d_in[10];
  const float* Wg_b  = (const float*)d_in[11];
  const int* story = (const int*)d_in[12];
  const int* tgt   = (const int*)d_in[13];
  const int* lens  = (const int*)d_in[14];
  float* out = (float*)d_out;

  // ws layout (f32 offsets); total ~30.4 MB
  float* ws      = (float*)d_ws;
  float* h_ws    = ws;                        // 192000
  float* x_ws    = ws + 192000;               // 192000
  float* prob_ws = ws + 384000;               // 192000
  float* sw_ws   = ws + 576000;               // 512
  float* gi_ws   = ws + 576512;               // 576000
  float* gh_ws   = ws + 1152512;              // 576000
  float* pmax_ws = ws + 1728512;              // 151040
  float* psum_ws = ws + 1879552;              // 151040
  short* h_hi    = (short*)(ws + 2030592);    // 30*13*512 shorts (99840 f32)
  short* emb_bf  = (short*)(ws + 2130432);    // 1256*13*512 shorts (4179968 f32)
  short* Wih_hi  = (short*)(ws + 6310400);    // 75*13*512 shorts (249600 f32)
  short* Wih_lo  = (short*)(ws + 6560000);
  short* Whh_hi  = (short*)(ws + 6809600);
  short* Whh_lo  = (short*)(ws + 7059200);
  short* x_hi    = (short*)(ws + 7308800);    // 99840 f32 each
  short* x_lo    = (short*)(ws + 7408640);
  short* h_lo    = (short*)(ws + 7508480);    // ends 7608320

  k_cast_emb<<<2048, 256, 0, stream>>>(emb, emb_bf);
  k_cast_W<<<512, 256, 0, stream>>>(W_ih, W_hh, Wih_hi, Wih_lo, Whh_hi, Whh_lo);
  k_init_all<<<195, 256, 0, stream>>>(eh, semb, h_ws, x_ws,
                                      h_hi, h_lo, x_hi, x_lo);
  dim3 gg(4, 10, 2);
  k_gemm2_mfma<<<gg, 256, 0, stream>>>(x_hi, x_lo, h_hi, h_lo,
                                       Wih_hi, Wih_lo, Whh_hi, Whh_lo,
                                       gi_ws, gh_ws);
  for (int wi = 0; wi < TT; ++wi){
    k_att<<<BSR, 256, 0, stream>>>(enc, emb, b_ih, b_hh, Wr_w, Wr_b, Wg_w, Wg_b,
                                   tgt, lens, gi_ws, gh_ws, h_ws, x_ws,
                                   h_hi, h_lo, x_hi, x_lo,
                                   prob_ws, sw_ws, out, wi);
    dim3 gl(4, NBN);
    k_logits_mfma<<<gl, 256, 0, stream>>>(h_hi, emb_bf, out, pmax_ws, psum_ws, wi);
    k_fin_gemm2<<<BSR + 80, 256, 0, stream>>>(out, prob_ws, pmax_ws, psum_ws,
                                              sw_ws, story, lens, wi,
                                              x_hi, x_lo, h_hi, h_lo,
                                              Wih_hi, Wih_lo, Whh_hi, Whh_lo,
                                              gi_ws, gh_ws, (wi + 1 < TT) ? 1 : 0);
  }
}